// Round 4
// baseline (360.990 us; speedup 1.0000x reference)
//
#include <hip/hip_runtime.h>
#include <hip/hip_bf16.h>

// GroupFC: C[32768,1024] = A[32768,1024] @ W[1024,1024]^T + b[1024], fp32 in/out.
// R7: break the 2-barrier-per-K-tile drain structure (the m97 ceiling mechanism
// that pinned R3/R4/R6 at 100-155us).  Single-barrier pipelined K-loop:
//   - As[2], Bs[2] LDS double buffers (64 KB): iteration t computes buffer p=t&1
//     while staging tile t+1 into p^1.  ONE raw s_barrier per K-tile.
//   - Counted s_waitcnt vmcnt(8) before the barrier (t=1..13): requires only
//     B(t) + A(t+1) complete (they are the 12 oldest of 20 in-flight vm ops);
//     the 8 newest A(t+2) loads STAY IN FLIGHT across the barrier.  vmcnt is
//     never drained to 0 in the steady loop (T4).  Tail iters 14/15 use vmcnt(0).
//   - K-loop fully unrolled (16 tiles): LDS parity + A-reg ping-pong buffer
//     binding are compile-time (runtime-indexed reg arrays spill to scratch).
//   - A: fp32 reg-staged depth-2 (bufX/bufY), cvt->bf16, swizzled ds_write.
//     W: bf16 (2 MB pre-convert, L2-resident) via global_load_lds, pre-swizzled
//     source chunks.  sched_barrier(0)+lgkmcnt(0) pin ds_writes above each
//     barrier (cross-wave visibility).
//   - XCD-aware bijective grid swizzle kept (FETCH 265 -> ~105 MB).

#define M_DIM 32768
#define N_DIM 1024
#define K_DIM 1024
#define BM 128
#define BN 128
#define BK 64
#define NT (K_DIM / BK)   // 16 K-tiles

typedef __attribute__((ext_vector_type(8))) short bf16x8;
typedef __attribute__((ext_vector_type(16))) float f32x16;
typedef __attribute__((ext_vector_type(8))) unsigned short ushort8v;

typedef const __attribute__((address_space(1))) unsigned int* gptr_t;
typedef __attribute__((address_space(3))) unsigned int* lptr_t;

static __device__ __forceinline__ unsigned short f2bf(float x) {
    union { __hip_bfloat16 h; unsigned short u; } cv;
    cv.h = __float2bfloat16(x);  // RNE
    return cv.u;
}

static __device__ __forceinline__ ushort8v cvt8(float4 lo, float4 hi) {
    ushort8v r;
    r[0] = f2bf(lo.x); r[1] = f2bf(lo.y); r[2] = f2bf(lo.z); r[3] = f2bf(lo.w);
    r[4] = f2bf(hi.x); r[5] = f2bf(hi.y); r[6] = f2bf(hi.z); r[7] = f2bf(hi.w);
    return r;
}

// ---------------- pass 1 (W only, 2 MB): fp32 -> bf16 ----------------
__global__ __launch_bounds__(256) void convert_f32_bf16(
    const float* __restrict__ in, unsigned short* __restrict__ out) {
    const int idx = (blockIdx.x * 256 + threadIdx.x) * 8;
    float4 v0 = *(const float4*)(in + idx);
    float4 v1 = *(const float4*)(in + idx + 4);
    ushort8v o;
    o[0] = f2bf(v0.x); o[1] = f2bf(v0.y); o[2] = f2bf(v0.z); o[3] = f2bf(v0.w);
    o[4] = f2bf(v1.x); o[5] = f2bf(v1.y); o[6] = f2bf(v1.z); o[7] = f2bf(v1.w);
    *(ushort8v*)(out + idx) = o;  // 16B store
}

// ---------------- fused pipelined GEMM ----------------
__global__ __launch_bounds__(256, 2) void gemm_fused(
    const float* __restrict__ A,            // [M,K] fp32
    const unsigned short* __restrict__ W,   // [N,K] bf16
    const float* __restrict__ bias,         // [N]
    float* __restrict__ C)                  // [M,N] fp32
{
    __shared__ unsigned short As[2][BM * BK];  // 2 x 16 KB
    __shared__ unsigned short Bs[2][BN * BK];  // 2 x 16 KB

    const int tid  = threadIdx.x;
    const int wave = tid >> 6;
    const int lane = tid & 63;

    // XCD-aware swizzle: 2048 blocks = 256 M-tiles x 8 N-tiles, 8 XCDs.
    const int bid = blockIdx.x;
    const int xcd = bid & 7;
    const int loc = bid >> 3;                      // 0..255
    const int bm0 = (xcd * 32 + (loc >> 3)) * BM;  // bijective over 256 M-tiles
    const int bn0 = (loc & 7) * BN;

    const int wr   = wave >> 1;        // wave row slab (64)
    const int wc   = wave & 1;         // wave col slab (64)
    const int l31  = lane & 31;
    const int half = lane >> 5;        // 0..1

    f32x16 acc[2][2];
#pragma unroll
    for (int i = 0; i < 2; ++i)
#pragma unroll
        for (int j = 0; j < 2; ++j)
#pragma unroll
            for (int r = 0; r < 16; ++r)
                acc[i][j][r] = 0.f;

    const float* Ag          = A + (size_t)bm0 * K_DIM;
    const unsigned short* Wg = W + (size_t)bn0 * K_DIM;

    // Per-thread A staging descriptors: 4 chunks of 8 fp32 (=8 bf16 out) each.
    int aoff[4];   // element offset within tile-row space (add kt at use)
    int lslot[4];  // LDS slot (16B units) for the swizzled bf16 write
#pragma unroll
    for (int q = 0; q < 4; ++q) {
        const int s   = q * 256 + tid;
        const int row = s >> 3;                       // 0..127
        const int cn  = s & 7;                        // chunk col 0..7
        aoff[q]  = row * K_DIM + cn * 8;
        lslot[q] = row * 8 + (cn ^ (row & 7));
    }

    float4 bufX[4][2], bufY[4][2];  // depth-2 ping-pong A staging (32+32 VGPR)

    auto ISSUEB = [&](int kt, int d) {   // 4 x global_load_lds dwordx4 -> Bs[d]
#pragma unroll
        for (int q = 0; q < 4; ++q) {
            const int s     = q * 256 + wave * 64 + lane;
            const int row   = s >> 3;
            const int c     = (s & 7) ^ (row & 7);
            const int goff  = row * K_DIM + kt + c * 8;   // bf16 elems
            const int lbase = (q * 256 + wave * 64) * 8;  // wave-uniform
            __builtin_amdgcn_global_load_lds((gptr_t)(Wg + goff),
                                             (lptr_t)(&Bs[d][lbase]), 16, 0, 0);
        }
    };
    auto LOADA = [&](float4 (&buf)[4][2], int kt) {  // 8 global_load_dwordx4
        if (kt < K_DIM) {
#pragma unroll
            for (int q = 0; q < 4; ++q) {
                const float* src = Ag + aoff[q] + kt;
                buf[q][0] = *(const float4*)(src);
                buf[q][1] = *(const float4*)(src + 4);
            }
        }
    };
    auto CVTW = [&](float4 (&buf)[4][2], int d) {    // cvt + swizzled ds_write_b128
#pragma unroll
        for (int q = 0; q < 4; ++q)
            *(ushort8v*)(&As[d][lslot[q] * 8]) = cvt8(buf[q][0], buf[q][1]);
    };

    // Prologue: stage tile 0; preload A tiles 0,1,2.
    ISSUEB(0, 0);
    LOADA(bufX, 0);
    LOADA(bufY, BK);
    CVTW(bufX, 0);            // compiler waits A(0) (retires B(0) too: older in FIFO)
    LOADA(bufX, 2 * BK);
    __builtin_amdgcn_sched_barrier(0);
    asm volatile("s_waitcnt lgkmcnt(0)");
    __builtin_amdgcn_s_barrier();

#pragma unroll
    for (int t = 0; t < NT; ++t) {
        const int p = t & 1;

        if (t > 0) {
            // Counted pre-barrier wait: B(t) (+ older A(t+1)) must be resident;
            // the 8 A(t+2) loads stay in flight ACROSS the barrier.
            if (t <= NT - 3) asm volatile("s_waitcnt vmcnt(8)");
            else             asm volatile("s_waitcnt vmcnt(0)");   // t=14,15 tail
            __builtin_amdgcn_s_barrier();
        }

        if (t < NT - 1) {
            // Stage tile t+1 into buffers p^1 (read next iteration).
            ISSUEB((t + 1) * BK, p ^ 1);
            if (t & 1) { CVTW(bufX, p ^ 1); LOADA(bufX, (t + 3) * BK); }
            else       { CVTW(bufY, p ^ 1); LOADA(bufY, (t + 3) * BK); }
        }

        // Compute tile t from As[p], Bs[p]: 4 k-steps, 16 x mfma_32x32x16_bf16.
#pragma unroll
        for (int ks = 0; ks < 4; ++ks) {
            const int kc = ks * 2 + half;          // 8-elem chunk index
            bf16x8 af[2], bfv[2];
#pragma unroll
            for (int i = 0; i < 2; ++i) {
                const int arw = wr * 64 + i * 32 + l31;
                af[i]  = *(const bf16x8*)(&As[p][arw * 64 + (kc ^ (arw & 7)) * 8]);
                const int brw = wc * 64 + i * 32 + l31;
                bfv[i] = *(const bf16x8*)(&Bs[p][brw * 64 + (kc ^ (brw & 7)) * 8]);
            }
#pragma unroll
            for (int i = 0; i < 2; ++i)
#pragma unroll
                for (int j = 0; j < 2; ++j)
                    acc[i][j] = __builtin_amdgcn_mfma_f32_32x32x16_bf16(
                        af[i], bfv[j], acc[i][j], 0, 0, 0);
        }

        if (t < NT - 1) {
            // Pin this iteration's ds_writes above the next barrier, then make
            // them visible (lgkmcnt(0)) before any wave crosses it.
            __builtin_amdgcn_sched_barrier(0);
            asm volatile("s_waitcnt lgkmcnt(0)");
        }
    }

    // Epilogue: +bias, fp32 store.
    // C/D 32x32: col = lane&31, row = (reg&3) + 8*(reg>>2) + 4*(lane>>5)  [m74/m101]
#pragma unroll
    for (int j = 0; j < 2; ++j) {
        const int col = bn0 + wc * 64 + j * 32 + l31;
        const float bj = bias[col];
#pragma unroll
        for (int i = 0; i < 2; ++i) {
            const int rbase = bm0 + wr * 64 + i * 32 + 4 * half;
#pragma unroll
            for (int reg = 0; reg < 16; ++reg) {
                const int row = rbase + (reg & 3) + 8 * (reg >> 2);
                C[(size_t)row * N_DIM + col] = acc[i][j][reg] + bj;
            }
        }
    }
}

// ---------------- fallback (fully fused, no workspace) ----------------
#define LDK 40
__global__ __launch_bounds__(256) void groupfc_fused(
    const float* __restrict__ A, const float* __restrict__ W,
    const float* __restrict__ bias, float* __restrict__ C)
{
    __shared__ unsigned short Asf[BM * LDK];
    __shared__ unsigned short Bsf[BN * LDK];
    const int tid = threadIdx.x;
    const int bm0 = blockIdx.x * BM, bn0 = blockIdx.y * BN;
    const int wave = tid >> 6, lane = tid & 63;
    const int wr = wave >> 1, wc = wave & 1;
    const int l15 = lane & 15, quad = lane >> 4;
    typedef __attribute__((ext_vector_type(4))) float f32x4;
    f32x4 acc[4][4];
#pragma unroll
    for (int i = 0; i < 4; ++i)
#pragma unroll
        for (int j = 0; j < 4; ++j) acc[i][j] = (f32x4){0.f, 0.f, 0.f, 0.f};
    const int srow = tid >> 3, sf4 = tid & 7;
    const float* Ag = A + bm0 * K_DIM;
    const float* Wg = W + bn0 * K_DIM;
    for (int kt = 0; kt < K_DIM; kt += 32) {
        __syncthreads();
        float4 av[4], bv[4];
#pragma unroll
        for (int q = 0; q < 4; ++q) {
            const int row = q * 32 + srow;
            av[q] = *(const float4*)(Ag + row * K_DIM + kt + sf4 * 4);
            bv[q] = *(const float4*)(Wg + row * K_DIM + kt + sf4 * 4);
        }
#pragma unroll
        for (int q = 0; q < 4; ++q) {
            const int row = q * 32 + srow;
            ushort4 a16, b16;
            a16.x = f2bf(av[q].x); a16.y = f2bf(av[q].y);
            a16.z = f2bf(av[q].z); a16.w = f2bf(av[q].w);
            b16.x = f2bf(bv[q].x); b16.y = f2bf(bv[q].y);
            b16.z = f2bf(bv[q].z); b16.w = f2bf(bv[q].w);
            *(ushort4*)(&Asf[row * LDK + sf4 * 4]) = a16;
            *(ushort4*)(&Bsf[row * LDK + sf4 * 4]) = b16;
        }
        __syncthreads();
        bf16x8 af[4], bfv[4];
#pragma unroll
        for (int i = 0; i < 4; ++i) {
            af[i]  = *(const bf16x8*)(&Asf[(wr * 64 + i * 16 + l15) * LDK + quad * 8]);
            bfv[i] = *(const bf16x8*)(&Bsf[(wc * 64 + i * 16 + l15) * LDK + quad * 8]);
        }
#pragma unroll
        for (int i = 0; i < 4; ++i)
#pragma unroll
            for (int j = 0; j < 4; ++j)
                acc[i][j] = __builtin_amdgcn_mfma_f32_16x16x32_bf16(af[i], bfv[j], acc[i][j], 0, 0, 0);
    }
#pragma unroll
    for (int j = 0; j < 4; ++j) {
        const int col = bn0 + wc * 64 + j * 16 + l15;
        const float bj = bias[col];
#pragma unroll
        for (int i = 0; i < 4; ++i) {
            const int row0 = bm0 + wr * 64 + i * 16 + quad * 4;
#pragma unroll
            for (int r = 0; r < 4; ++r) C[(row0 + r) * N_DIM + col] = acc[i][j][r] + bj;
        }
    }
}

extern "C" void kernel_launch(void* const* d_in, const int* in_sizes, int n_in,
                              void* d_out, int out_size, void* d_ws, size_t ws_size,
                              hipStream_t stream) {
    const float* A    = (const float*)d_in[0];
    const float* W    = (const float*)d_in[1];
    const float* bias = (const float*)d_in[2];
    float* C          = (float*)d_out;

    const size_t w_elems = (size_t)N_DIM * K_DIM;
    const size_t need    = w_elems * sizeof(unsigned short);  // 2 MB

    if (ws_size >= need) {
        unsigned short* Wbf = (unsigned short*)d_ws;
        convert_f32_bf16<<<dim3(w_elems / (256 * 8)), dim3(256), 0, stream>>>(W, Wbf);
        gemm_fused<<<dim3((M_DIM / BM) * (N_DIM / BN)), dim3(256), 0, stream>>>(A, Wbf, bias, C);
    } else {
        dim3 grid(M_DIM / BM, N_DIM / BN);
        groupfc_fused<<<grid, dim3(256), 0, stream>>>(A, W, bias, C);
    }
}

// Round 5
// 310.447 us; speedup vs baseline: 1.1628x; 1.1628x over previous
//
#include <hip/hip_runtime.h>
#include <hip/hip_bf16.h>

// GroupFC: C[32768,1024] = A[32768,1024] @ W[1024,1024]^T + b[1024], fp32 in/out.
// R8: R5's fused design (A staged fp32 via global_load_lds, cvt->bf16 at
// fragment-load time) with the LDS swizzle FIXED:
//   - R5's pair-preserving XOR (row&7)<<1 only hit 4 of 8 bank groups ->
//     8-way conflicts, SQ_LDS_BANK_CONFLICT=86M, 233us.  Now slot = c^(row&7)
//     (full low-3-bit XOR, same spread as the proven B-side): bank group
//     slot%8 distinct across rows 0..7 -> 4-way max (the b128 floor).
//   - Fragment's 8 floats land in slots {2kc^x, (2kc+1)^x} (x=row&7) -- not
//     contiguous, so read as TWO independent ds_read_b128 at computed slots.
//   - Skeleton = R3's proven 2-barrier pure-DMA loop (fastest measured: 102us):
//     single LDS buffer pair, global_load_lds for BOTH operands, no reg-staged
//     A, no ds_write, no hand vmcnt (R4/R6/R7 reg-staging all lost 50-100us).
//   - Fusion kept: A read once as fp32 (no 201MB convert pass); W bf16 2MB
//     pre-convert; XCD-aware bijective grid swizzle (fetch ~100MB).
// LDS = 32KB (A fp32) + 16KB (B bf16) = 48KB -> 3 blocks/CU.

#define M_DIM 32768
#define N_DIM 1024
#define K_DIM 1024
#define BM 128
#define BN 128
#define BK 64

typedef __attribute__((ext_vector_type(8))) short bf16x8;
typedef __attribute__((ext_vector_type(16))) float f32x16;
typedef __attribute__((ext_vector_type(8))) unsigned short ushort8v;

typedef const __attribute__((address_space(1))) unsigned int* gptr_t;
typedef __attribute__((address_space(3))) unsigned int* lptr_t;

static __device__ __forceinline__ unsigned short f2bf(float x) {
    union { __hip_bfloat16 h; unsigned short u; } cv;
    cv.h = __float2bfloat16(x);  // RNE
    return cv.u;
}

static __device__ __forceinline__ bf16x8 cvt8(float4 lo, float4 hi) {
    bf16x8 r;
    r[0] = (short)f2bf(lo.x); r[1] = (short)f2bf(lo.y);
    r[2] = (short)f2bf(lo.z); r[3] = (short)f2bf(lo.w);
    r[4] = (short)f2bf(hi.x); r[5] = (short)f2bf(hi.y);
    r[6] = (short)f2bf(hi.z); r[7] = (short)f2bf(hi.w);
    return r;
}

// ---------------- pass 1 (W only, 2 MB): fp32 -> bf16 ----------------
__global__ __launch_bounds__(256) void convert_f32_bf16(
    const float* __restrict__ in, unsigned short* __restrict__ out) {
    const int idx = (blockIdx.x * 256 + threadIdx.x) * 8;
    float4 v0 = *(const float4*)(in + idx);
    float4 v1 = *(const float4*)(in + idx + 4);
    ushort8v o;
    o[0] = f2bf(v0.x); o[1] = f2bf(v0.y); o[2] = f2bf(v0.z); o[3] = f2bf(v0.w);
    o[4] = f2bf(v1.x); o[5] = f2bf(v1.y); o[6] = f2bf(v1.z); o[7] = f2bf(v1.w);
    *(ushort8v*)(out + idx) = o;  // 16B store
}

// ---------------- fused GEMM: A fp32 staged via DMA, W bf16 ----------------
// A LDS: 128 rows x 16 chunks (chunk = 4 fp32 = 16B); global chunk c of row r
//        at slot c ^ (r&7).   (involution: src chunk for dest slot d = d^(r&7))
// B LDS: 128 rows x 8 chunks (chunk = 8 bf16 = 16B); slot c ^ (r&7).
// Both staged by global_load_lds with PRE-SWIZZLED global source (linear LDS
// dest in lane order -- the only layout gload_lds supports, m104/m173).
__global__ __launch_bounds__(256, 3) void gemm_fused(
    const float* __restrict__ A,            // [M,K] fp32
    const unsigned short* __restrict__ W,   // [N,K] bf16
    const float* __restrict__ bias,         // [N]
    float* __restrict__ C)                  // [M,N] fp32
{
    __shared__ float          As[BM * BK];  // 32 KB (fp32)
    __shared__ unsigned short Bs[BN * BK];  // 16 KB (bf16)

    const int tid  = threadIdx.x;
    const int wave = tid >> 6;
    const int lane = tid & 63;

    // XCD-aware swizzle: 2048 blocks = 256 M-tiles x 8 N-tiles, 8 XCDs.
    // bid%8 -> XCD; each XCD owns M-tiles [xcd*32, xcd*32+32), n fastest, so the
    // 8 blocks sharing an A-tile are time-adjacent on ONE per-XCD L2.
    const int bid = blockIdx.x;
    const int xcd = bid & 7;
    const int loc = bid >> 3;                      // 0..255
    const int bm0 = (xcd * 32 + (loc >> 3)) * BM;  // bijective over 256 M-tiles
    const int bn0 = (loc & 7) * BN;

    const int wr   = wave >> 1;        // wave row slab (64)
    const int wc   = wave & 1;         // wave col slab (64)
    const int l31  = lane & 31;
    const int half = lane >> 5;        // 0..1

    f32x16 acc[2][2];
#pragma unroll
    for (int i = 0; i < 2; ++i)
#pragma unroll
        for (int j = 0; j < 2; ++j)
#pragma unroll
            for (int r = 0; r < 16; ++r)
                acc[i][j][r] = 0.f;

    const float* Ag          = A + (size_t)bm0 * K_DIM;
    const unsigned short* Wg = W + (size_t)bn0 * K_DIM;

    for (int kt = 0; kt < K_DIM; kt += BK) {
        __syncthreads();  // previous compute's LDS reads done

        // A stage: 8 x global_load_lds dwordx4 (fp32 src, pre-swizzled chunk)
#pragma unroll
        for (int p = 0; p < 8; ++p) {
            const int s     = p * 256 + tid;                 // dest 16B chunk id
            const int row   = s >> 4;                        // 0..127
            const int c     = (s & 15) ^ (row & 7);          // src chunk (involution)
            const int goff  = row * K_DIM + kt + c * 4;      // fp32 elems
            const int lbase = (p * 256 + wave * 64) * 4;     // fp32 elems (wave-uniform)
            __builtin_amdgcn_global_load_lds((gptr_t)(Ag + goff), (lptr_t)(As + lbase), 16, 0, 0);
        }
        // B stage: 4 x global_load_lds dwordx4 (bf16 src, pre-swizzled chunk)
#pragma unroll
        for (int p = 0; p < 4; ++p) {
            const int s     = p * 256 + tid;
            const int row   = s >> 3;
            const int c     = (s & 7) ^ (row & 7);
            const int goff  = row * K_DIM + kt + c * 8;      // bf16 elems
            const int lbase = (p * 256 + wave * 64) * 8;     // bf16 elems (wave-uniform)
            __builtin_amdgcn_global_load_lds((gptr_t)(Wg + goff), (lptr_t)(Bs + lbase), 16, 0, 0);
        }

        __syncthreads();  // drains vmcnt(0): both tiles resident

        // Compute: 4 k-steps of K=16, 16 x mfma_f32_32x32x16_bf16.
        // A fragments: two independent ds_read_b128 at swizzled slots + 8 cvt
        // (packs to v_cvt_pk_bf16_f32); VALU co-schedules with MFMA (m114).
#pragma unroll
        for (int ks = 0; ks < 4; ++ks) {
            const int kc = ks * 2 + half;          // 8-elem chunk index 0..7
            bf16x8 af[2], bfv[2];
#pragma unroll
            for (int i = 0; i < 2; ++i) {
                const int arw = wr * 64 + i * 32 + l31;
                const int x   = arw & 7;
                const int s0  = (2 * kc) ^ x;                   // 16B slot of floats 0..3
                const int s1  = (2 * kc + 1) ^ x;               // 16B slot of floats 4..7
                const float4 f0 = *(const float4*)(As + arw * 64 + s0 * 4);
                const float4 f1 = *(const float4*)(As + arw * 64 + s1 * 4);
                af[i] = cvt8(f0, f1);
                const int brw = wc * 64 + i * 32 + l31;
                bfv[i] = *(const bf16x8*)(Bs + brw * 64 + (kc ^ (brw & 7)) * 8);
            }
#pragma unroll
            for (int i = 0; i < 2; ++i)
#pragma unroll
                for (int j = 0; j < 2; ++j)
                    acc[i][j] = __builtin_amdgcn_mfma_f32_32x32x16_bf16(
                        af[i], bfv[j], acc[i][j], 0, 0, 0);
        }
    }

    // Epilogue: +bias, fp32 store.
    // C/D 32x32: col = lane&31, row = (reg&3) + 8*(reg>>2) + 4*(lane>>5)  [m74/m101]
#pragma unroll
    for (int j = 0; j < 2; ++j) {
        const int col = bn0 + wc * 64 + j * 32 + l31;
        const float bj = bias[col];
#pragma unroll
        for (int i = 0; i < 2; ++i) {
            const int rbase = bm0 + wr * 64 + i * 32 + 4 * half;
#pragma unroll
            for (int reg = 0; reg < 16; ++reg) {
                const int row = rbase + (reg & 3) + 8 * (reg >> 2);
                C[(size_t)row * N_DIM + col] = acc[i][j][reg] + bj;
            }
        }
    }
}

// ---------------- fallback (fully fused, no workspace) ----------------
#define LDK 40
__global__ __launch_bounds__(256) void groupfc_fused(
    const float* __restrict__ A, const float* __restrict__ W,
    const float* __restrict__ bias, float* __restrict__ C)
{
    __shared__ unsigned short Asf[BM * LDK];
    __shared__ unsigned short Bsf[BN * LDK];
    const int tid = threadIdx.x;
    const int bm0 = blockIdx.x * BM, bn0 = blockIdx.y * BN;
    const int wave = tid >> 6, lane = tid & 63;
    const int wr = wave >> 1, wc = wave & 1;
    const int l15 = lane & 15, quad = lane >> 4;
    typedef __attribute__((ext_vector_type(4))) float f32x4;
    f32x4 acc[4][4];
#pragma unroll
    for (int i = 0; i < 4; ++i)
#pragma unroll
        for (int j = 0; j < 4; ++j) acc[i][j] = (f32x4){0.f, 0.f, 0.f, 0.f};
    const int srow = tid >> 3, sf4 = tid & 7;
    const float* Ag = A + bm0 * K_DIM;
    const float* Wg = W + bn0 * K_DIM;
    for (int kt = 0; kt < K_DIM; kt += 32) {
        __syncthreads();
        float4 av[4], bv[4];
#pragma unroll
        for (int q = 0; q < 4; ++q) {
            const int row = q * 32 + srow;
            av[q] = *(const float4*)(Ag + row * K_DIM + kt + sf4 * 4);
            bv[q] = *(const float4*)(Wg + row * K_DIM + kt + sf4 * 4);
        }
#pragma unroll
        for (int q = 0; q < 4; ++q) {
            const int row = q * 32 + srow;
            ushort4 a16, b16;
            a16.x = f2bf(av[q].x); a16.y = f2bf(av[q].y);
            a16.z = f2bf(av[q].z); a16.w = f2bf(av[q].w);
            b16.x = f2bf(bv[q].x); b16.y = f2bf(bv[q].y);
            b16.z = f2bf(bv[q].z); b16.w = f2bf(bv[q].w);
            *(ushort4*)(&Asf[row * LDK + sf4 * 4]) = a16;
            *(ushort4*)(&Bsf[row * LDK + sf4 * 4]) = b16;
        }
        __syncthreads();
        bf16x8 af[4], bfv[4];
#pragma unroll
        for (int i = 0; i < 4; ++i) {
            af[i]  = *(const bf16x8*)(&Asf[(wr * 64 + i * 16 + l15) * LDK + quad * 8]);
            bfv[i] = *(const bf16x8*)(&Bsf[(wc * 64 + i * 16 + l15) * LDK + quad * 8]);
        }
#pragma unroll
        for (int i = 0; i < 4; ++i)
#pragma unroll
            for (int j = 0; j < 4; ++j)
                acc[i][j] = __builtin_amdgcn_mfma_f32_16x16x32_bf16(af[i], bfv[j], acc[i][j], 0, 0, 0);
    }
#pragma unroll
    for (int j = 0; j < 4; ++j) {
        const int col = bn0 + wc * 64 + j * 16 + l15;
        const float bj = bias[col];
#pragma unroll
        for (int i = 0; i < 4; ++i) {
            const int row0 = bm0 + wr * 64 + i * 16 + quad * 4;
#pragma unroll
            for (int r = 0; r < 4; ++r) C[(row0 + r) * N_DIM + col] = acc[i][j][r] + bj;
        }
    }
}

extern "C" void kernel_launch(void* const* d_in, const int* in_sizes, int n_in,
                              void* d_out, int out_size, void* d_ws, size_t ws_size,
                              hipStream_t stream) {
    const float* A    = (const float*)d_in[0];
    const float* W    = (const float*)d_in[1];
    const float* bias = (const float*)d_in[2];
    float* C          = (float*)d_out;

    const size_t w_elems = (size_t)N_DIM * K_DIM;
    const size_t need    = w_elems * sizeof(unsigned short);  // 2 MB

    if (ws_size >= need) {
        unsigned short* Wbf = (unsigned short*)d_ws;
        convert_f32_bf16<<<dim3(w_elems / (256 * 8)), dim3(256), 0, stream>>>(W, Wbf);
        gemm_fused<<<dim3((M_DIM / BM) * (N_DIM / BN)), dim3(256), 0, stream>>>(A, Wbf, bias, C);
    } else {
        dim3 grid(M_DIM / BM, N_DIM / BN);
        groupfc_fused<<<grid, dim3(256), 0, stream>>>(A, W, bias, C);
    }
}

// Round 6
// 301.620 us; speedup vs baseline: 1.1968x; 1.0293x over previous
//
#include <hip/hip_runtime.h>
#include <hip/hip_bf16.h>

// GroupFC: C[32768,1024] = A[32768,1024] @ W[1024,1024]^T + b[1024], fp32 in/out.
// R9: compose the three individually-proven pieces; abandon A-fusion.
//   Ledger: every fused-A variant paid 50-100us over the pure-DMA skeleton
//   (R4 150 / R6 155 / R7 202 / R8 152 vs R3 102us): reg-staging adds a serial
//   cvt+ds_write phase (R4/R6/R7) and fp32-in-LDS adds 1.5x DMA + 1.5x LDS
//   reads + cvt on the critical path (R8).  So:
//   (1) A pre-convert pass (R0-proven): 201MB, ~35-50us, restores bf16 datapath.
//   (2) gemm = R3's exact skeleton (102us measured WHILE hauling 406MB):
//       global_load_lds for both operands, 2-barrier loop, 16+16KB LDS, 76 VGPR.
//   (3) + R8's XCD-bijective grid swizzle (measured: fetch 265->107MB).  R3
//       lacked it -- its A-tiles round-robined across 8 non-coherent L2s (4x
//       refetch).  bf16 A + swizzle => ~75MB fetch: no more BW contention.
//   Side benefit: 32KB LDS/block -> up to 5 blocks/CU (R3 had 3 at 48KB).

#define M_DIM 32768
#define N_DIM 1024
#define K_DIM 1024
#define BM 128
#define BN 128
#define BK 64

typedef __attribute__((ext_vector_type(8))) short bf16x8;
typedef __attribute__((ext_vector_type(16))) float f32x16;
typedef __attribute__((ext_vector_type(8))) unsigned short ushort8v;

typedef const __attribute__((address_space(1))) unsigned int* gptr_t;
typedef __attribute__((address_space(3))) unsigned int* lptr_t;

static __device__ __forceinline__ unsigned short f2bf(float x) {
    union { __hip_bfloat16 h; unsigned short u; } cv;
    cv.h = __float2bfloat16(x);  // RNE
    return cv.u;
}

// ---------------- pass 1: fp32 -> bf16 convert (A: 201MB, W: 6MB) ----------
__global__ __launch_bounds__(256) void convert_f32_bf16(
    const float* __restrict__ in, unsigned short* __restrict__ out) {
    const int idx = (blockIdx.x * 256 + threadIdx.x) * 8;
    float4 v0 = *(const float4*)(in + idx);
    float4 v1 = *(const float4*)(in + idx + 4);
    ushort8v o;
    o[0] = f2bf(v0.x); o[1] = f2bf(v0.y); o[2] = f2bf(v0.z); o[3] = f2bf(v0.w);
    o[4] = f2bf(v1.x); o[5] = f2bf(v1.y); o[6] = f2bf(v1.z); o[7] = f2bf(v1.w);
    *(ushort8v*)(out + idx) = o;  // 16B store
}

// ---------------- pass 2: bf16 MFMA GEMM (R3 skeleton + XCD swizzle) --------
// LDS: tile as 128 rows x 8 chunks (chunk = 8 bf16 = 16B); chunk c of row r at
// slot r*8 + (c ^ (r&7)).  global_load_lds fills slots in lane order; each lane
// fetches the global chunk belonging in its slot (pre-swizzled source, m173).
__global__ __launch_bounds__(256) void gemm_bf16(
    const unsigned short* __restrict__ A,   // [M,K] bf16
    const unsigned short* __restrict__ W,   // [N,K] bf16
    const float* __restrict__ bias,         // [N]
    float* __restrict__ C)                  // [M,N] fp32
{
    __shared__ unsigned short As[BM * BK];  // 16 KB
    __shared__ unsigned short Bs[BN * BK];  // 16 KB

    const int tid  = threadIdx.x;
    const int wave = tid >> 6;
    const int lane = tid & 63;

    // XCD-aware bijective swizzle: 2048 blocks = 256 M-tiles x 8 N-tiles,
    // 8 XCDs.  bid%8 -> XCD (dispatch round-robin); each XCD owns M-tiles
    // [xcd*32, xcd*32+32), n fastest -> the 8 blocks sharing an A-tile are
    // time-adjacent on ONE per-XCD L2 (fixes R3's 4x A re-fetch).
    const int bid = blockIdx.x;
    const int xcd = bid & 7;
    const int loc = bid >> 3;                      // 0..255
    const int bm0 = (xcd * 32 + (loc >> 3)) * BM;  // bijective over 256 M-tiles
    const int bn0 = (loc & 7) * BN;

    const int wr   = wave >> 1;        // wave row slab (64)
    const int wc   = wave & 1;         // wave col slab (64)
    const int l31  = lane & 31;
    const int half = lane >> 5;        // 0..1

    f32x16 acc[2][2];
#pragma unroll
    for (int i = 0; i < 2; ++i)
#pragma unroll
        for (int j = 0; j < 2; ++j)
#pragma unroll
            for (int r = 0; r < 16; ++r)
                acc[i][j][r] = 0.f;

    const unsigned short* Ag = A + (size_t)bm0 * K_DIM;
    const unsigned short* Wg = W + (size_t)bn0 * K_DIM;

    for (int kt = 0; kt < K_DIM; kt += BK) {
        __syncthreads();
#pragma unroll
        for (int p = 0; p < 4; ++p) {
            const int s     = p * 256 + wave * 64 + lane;
            const int row   = s >> 3;
            const int c     = (s & 7) ^ (row & 7);
            const int goff  = row * K_DIM + kt + c * 8;    // elems
            const int lbase = (p * 256 + wave * 64) * 8;   // elems (wave-uniform)
            __builtin_amdgcn_global_load_lds((gptr_t)(Ag + goff), (lptr_t)(As + lbase), 16, 0, 0);
            __builtin_amdgcn_global_load_lds((gptr_t)(Wg + goff), (lptr_t)(Bs + lbase), 16, 0, 0);
        }
        __syncthreads();

#pragma unroll
        for (int ks = 0; ks < 4; ++ks) {           // 4 k-steps of K=16
            const int kc = ks * 2 + half;          // chunk index (8 elems)
            bf16x8 af[2], bfv[2];
#pragma unroll
            for (int i = 0; i < 2; ++i) {
                const int arw = wr * 64 + i * 32 + l31;
                af[i]  = *(const bf16x8*)(As + arw * 64 + (kc ^ (arw & 7)) * 8);
                const int brw = wc * 64 + i * 32 + l31;
                bfv[i] = *(const bf16x8*)(Bs + brw * 64 + (kc ^ (brw & 7)) * 8);
            }
#pragma unroll
            for (int i = 0; i < 2; ++i)
#pragma unroll
                for (int j = 0; j < 2; ++j)
                    acc[i][j] = __builtin_amdgcn_mfma_f32_32x32x16_bf16(
                        af[i], bfv[j], acc[i][j], 0, 0, 0);
        }
    }

    // Epilogue: +bias, fp32 store.
    // C/D 32x32: col = lane&31, row = (reg&3) + 8*(reg>>2) + 4*(lane>>5)  [m74/m101]
#pragma unroll
    for (int j = 0; j < 2; ++j) {
        const int col = bn0 + wc * 64 + j * 32 + l31;
        const float bj = bias[col];
#pragma unroll
        for (int i = 0; i < 2; ++i) {
            const int rbase = bm0 + wr * 64 + i * 32 + 4 * half;
#pragma unroll
            for (int reg = 0; reg < 16; ++reg) {
                const int row = rbase + (reg & 3) + 8 * (reg >> 2);
                C[(size_t)row * N_DIM + col] = acc[i][j][reg] + bj;
            }
        }
    }
}

// ---------------- fallback (fully fused, no workspace) ----------------
#define LDK 40
__global__ __launch_bounds__(256) void groupfc_fused(
    const float* __restrict__ A, const float* __restrict__ W,
    const float* __restrict__ bias, float* __restrict__ C)
{
    __shared__ unsigned short Asf[BM * LDK];
    __shared__ unsigned short Bsf[BN * LDK];
    const int tid = threadIdx.x;
    const int bm0 = blockIdx.x * BM, bn0 = blockIdx.y * BN;
    const int wave = tid >> 6, lane = tid & 63;
    const int wr = wave >> 1, wc = wave & 1;
    const int l15 = lane & 15, quad = lane >> 4;
    typedef __attribute__((ext_vector_type(4))) float f32x4;
    f32x4 acc[4][4];
#pragma unroll
    for (int i = 0; i < 4; ++i)
#pragma unroll
        for (int j = 0; j < 4; ++j) acc[i][j] = (f32x4){0.f, 0.f, 0.f, 0.f};
    const int srow = tid >> 3, sf4 = tid & 7;
    const float* Ag = A + bm0 * K_DIM;
    const float* Wg = W + bn0 * K_DIM;
    for (int kt = 0; kt < K_DIM; kt += 32) {
        __syncthreads();
        float4 av[4], bv[4];
#pragma unroll
        for (int q = 0; q < 4; ++q) {
            const int row = q * 32 + srow;
            av[q] = *(const float4*)(Ag + row * K_DIM + kt + sf4 * 4);
            bv[q] = *(const float4*)(Wg + row * K_DIM + kt + sf4 * 4);
        }
#pragma unroll
        for (int q = 0; q < 4; ++q) {
            const int row = q * 32 + srow;
            ushort4 a16, b16;
            a16.x = f2bf(av[q].x); a16.y = f2bf(av[q].y);
            a16.z = f2bf(av[q].z); a16.w = f2bf(av[q].w);
            b16.x = f2bf(bv[q].x); b16.y = f2bf(bv[q].y);
            b16.z = f2bf(bv[q].z); b16.w = f2bf(bv[q].w);
            *(ushort4*)(&Asf[row * LDK + sf4 * 4]) = a16;
            *(ushort4*)(&Bsf[row * LDK + sf4 * 4]) = b16;
        }
        __syncthreads();
        bf16x8 af[4], bfv[4];
#pragma unroll
        for (int i = 0; i < 4; ++i) {
            af[i]  = *(const bf16x8*)(&Asf[(wr * 64 + i * 16 + l15) * LDK + quad * 8]);
            bfv[i] = *(const bf16x8*)(&Bsf[(wc * 64 + i * 16 + l15) * LDK + quad * 8]);
        }
#pragma unroll
        for (int i = 0; i < 4; ++i)
#pragma unroll
            for (int j = 0; j < 4; ++j)
                acc[i][j] = __builtin_amdgcn_mfma_f32_16x16x32_bf16(af[i], bfv[j], acc[i][j], 0, 0, 0);
    }
#pragma unroll
    for (int j = 0; j < 4; ++j) {
        const int col = bn0 + wc * 64 + j * 16 + l15;
        const float bj = bias[col];
#pragma unroll
        for (int i = 0; i < 4; ++i) {
            const int row0 = bm0 + wr * 64 + i * 16 + quad * 4;
#pragma unroll
            for (int r = 0; r < 4; ++r) C[(row0 + r) * N_DIM + col] = acc[i][j][r] + bj;
        }
    }
}

extern "C" void kernel_launch(void* const* d_in, const int* in_sizes, int n_in,
                              void* d_out, int out_size, void* d_ws, size_t ws_size,
                              hipStream_t stream) {
    const float* A    = (const float*)d_in[0];
    const float* W    = (const float*)d_in[1];
    const float* bias = (const float*)d_in[2];
    float* C          = (float*)d_out;

    const size_t a_elems = (size_t)M_DIM * K_DIM;
    const size_t w_elems = (size_t)N_DIM * K_DIM;
    const size_t need    = (a_elems + w_elems) * sizeof(unsigned short);  // ~69 MB

    if (ws_size >= need) {
        unsigned short* Abf = (unsigned short*)d_ws;
        unsigned short* Wbf = Abf + a_elems;
        convert_f32_bf16<<<dim3(a_elems / (256 * 8)), dim3(256), 0, stream>>>(A, Abf);
        convert_f32_bf16<<<dim3(w_elems / (256 * 8)), dim3(256), 0, stream>>>(W, Wbf);
        gemm_bf16<<<dim3((M_DIM / BM) * (N_DIM / BN)), dim3(256), 0, stream>>>(Abf, Wbf, bias, C);
    } else {
        dim3 grid(M_DIM / BM, N_DIM / BN);
        groupfc_fused<<<grid, dim3(256), 0, stream>>>(A, W, bias, C);
    }
}